// Round 1
// baseline (518.148 us; speedup 1.0000x reference)
//
#include <hip/hip_runtime.h>
#include <hip/hip_bf16.h>
#include <stdint.h>

#define N_TOK 4096
#define C_DIM 1024
#define F_DIM 2048
#define E_NUM 8
#define SMAX 9216       // 72 tiles * 128 rows: max padded slot count
#define TILES_MAX 72
#define RBLK 1024       // router blocks (4 tokens each)

typedef __attribute__((ext_vector_type(4))) float f32x4;
typedef __attribute__((ext_vector_type(8))) short s16x8;

__device__ __forceinline__ uint16_t f2bf(float f) {
    unsigned x;
    __builtin_memcpy(&x, &f, 4);
    unsigned r = (x + 0x7fffu + ((x >> 16) & 1u)) >> 16;  // RNE
    return (uint16_t)r;
}
__device__ __forceinline__ float bf2f(uint16_t u) {
    unsigned v = (unsigned)u << 16;
    float f;
    __builtin_memcpy(&f, &v, 4);
    return f;
}

#define GLL16(gp, lp)                                                                  \
    __builtin_amdgcn_global_load_lds((const __attribute__((address_space(1))) unsigned int*)(gp), \
                                     (__attribute__((address_space(3))) unsigned int*)(lp), 16, 0, 0)

// ---------------- router: fp32 logits -> softmax -> top2; LDS-aggregated partials ----------------
__global__ void router_kernel(const float* __restrict__ x, const float* __restrict__ rw,
                              int* __restrict__ topk_idx, float* __restrict__ topk_w,
                              float* __restrict__ psum_part, int* __restrict__ cnt_part) {
    __shared__ float s_p[E_NUM];
    __shared__ int s_c[E_NUM];
    if (threadIdx.x < E_NUM) { s_p[threadIdx.x] = 0.f; s_c[threadIdx.x] = 0; }
    __syncthreads();

    int lane = threadIdx.x & 63;
    int wv = threadIdx.x >> 6;
    int t = blockIdx.x * 4 + wv;

    const float* xr = x + (size_t)t * C_DIM + lane * 16;
    float xs[16];
    for (int i = 0; i < 4; i++) *(float4*)&xs[i * 4] = *(const float4*)(xr + i * 4);

    float acc[E_NUM];
    for (int e = 0; e < E_NUM; e++) {
        const float* wr = rw + e * C_DIM + lane * 16;
        float s = 0.f;
        for (int i = 0; i < 4; i++) {
            float4 v = *(const float4*)(wr + i * 4);
            s += xs[i * 4] * v.x + xs[i * 4 + 1] * v.y + xs[i * 4 + 2] * v.z + xs[i * 4 + 3] * v.w;
        }
        acc[e] = s;
    }
    for (int off = 32; off > 0; off >>= 1)
        for (int e = 0; e < E_NUM; e++) acc[e] += __shfl_down(acc[e], off, 64);

    if (lane == 0) {
        float m = acc[0];
        for (int e = 1; e < E_NUM; e++) m = fmaxf(m, acc[e]);
        float p[E_NUM], s = 0.f;
        for (int e = 0; e < E_NUM; e++) { p[e] = __expf(acc[e] - m); s += p[e]; }
        float inv = 1.f / s;
        for (int e = 0; e < E_NUM; e++) { p[e] *= inv; atomicAdd(&s_p[e], p[e]); }  // LDS atomic
        int i0 = 0;
        for (int e = 1; e < E_NUM; e++) if (p[e] > p[i0]) i0 = e;         // ties -> lowest idx
        int i1 = (i0 == 0) ? 1 : 0;
        for (int e = 0; e < E_NUM; e++) if (e != i0 && p[e] > p[i1]) i1 = e;
        float w0 = p[i0], w1 = p[i1], wsum = w0 + w1;
        topk_idx[t * 2] = i0; topk_idx[t * 2 + 1] = i1;
        topk_w[t * 2] = w0 / wsum; topk_w[t * 2 + 1] = w1 / wsum;
        atomicAdd(&s_c[i0], 1); atomicAdd(&s_c[i1], 1);                   // LDS atomic
    }
    __syncthreads();
    if (threadIdx.x < E_NUM) {
        psum_part[blockIdx.x * E_NUM + threadIdx.x] = s_p[threadIdx.x];
        cnt_part[blockIdx.x * E_NUM + threadIdx.x] = s_c[threadIdx.x];
    }
}

// ---------------- reduce partials -> counts/psum; plan offsets+tiles; aux loss ----------------
__global__ void reduce_plan_kernel(const float* __restrict__ psum_part, const int* __restrict__ cnt_part,
                                   int* __restrict__ offsets, int* __restrict__ tile_expert,
                                   int* __restrict__ tile_row0, float* __restrict__ aux_out) {
    __shared__ float sp[256];
    __shared__ int sc[256];
    __shared__ int s_count[E_NUM];
    __shared__ float s_psum[E_NUM];
    int e = threadIdx.x >> 5, i = threadIdx.x & 31;
    float fp = 0.f; int c = 0;
    for (int j = i; j < RBLK; j += 32) { fp += psum_part[j * E_NUM + e]; c += cnt_part[j * E_NUM + e]; }
    sp[threadIdx.x] = fp; sc[threadIdx.x] = c;
    __syncthreads();
    for (int s = 16; s > 0; s >>= 1) {
        if (i < s) { sp[threadIdx.x] += sp[threadIdx.x + s]; sc[threadIdx.x] += sc[threadIdx.x + s]; }
        __syncthreads();
    }
    if (i == 0) { s_count[e] = sc[threadIdx.x]; s_psum[e] = sp[threadIdx.x]; }
    __syncthreads();
    if (threadIdx.x == 0) {
        int off = 0, t = 0;
        for (int ee = 0; ee < E_NUM; ee++) {
            offsets[ee] = off;
            int n = s_count[ee];
            int nt = (n + 127) >> 7;
            for (int k = 0; k < nt; k++) { tile_expert[t] = ee; tile_row0[t] = off + k * 128; t++; }
            off += nt * 128;
        }
        offsets[E_NUM] = off;
        for (; t < TILES_MAX; t++) tile_expert[t] = -1;
        float s = 0.f;
        for (int ee = 0; ee < E_NUM; ee++) { float a = s_psum[ee] * (1.f / N_TOK); s += a * a; }
        aux_out[0] = 8.f * s;
    }
}

// ---------------- assign: block-aggregated slot reservation + inverse map ----------------
__global__ void assign_kernel(const int* __restrict__ topk_idx, const float* __restrict__ topk_w,
                              const int* __restrict__ offsets, int* __restrict__ count2,
                              int* __restrict__ slot_map, float* __restrict__ slot_w,
                              int* __restrict__ tok_slot) {
    __shared__ int h[E_NUM];
    __shared__ int base[E_NUM];
    if (threadIdx.x < E_NUM) h[threadIdx.x] = 0;
    __syncthreads();
    int item = blockIdx.x * 256 + threadIdx.x;
    int e = topk_idx[item];
    int rank = atomicAdd(&h[e], 1);         // LDS atomic
    __syncthreads();
    if (threadIdx.x < E_NUM)
        base[threadIdx.x] = offsets[threadIdx.x] + atomicAdd(&count2[threadIdx.x], h[threadIdx.x]);
    __syncthreads();
    int slot = base[e] + rank;
    slot_map[slot] = item;
    slot_w[slot] = topk_w[item];
    tok_slot[item] = slot;
}

// ---------------- gather: copy+convert x rows (fp32 -> bf16) into slot space ----------------
__global__ void gather_kernel(const float* __restrict__ x, const int* __restrict__ slot_map,
                              uint16_t* __restrict__ x_slots) {
    int slot = blockIdx.x;
    int item = slot_map[slot];
    if (item < 0) return;  // padding row: leave poison (tiny denormals, harmless)
    int t = item >> 1;
    float4 v = *(const float4*)(x + (size_t)t * C_DIM + threadIdx.x * 4);
    union { uint16_t u[4]; uint2 q; } r;
    r.u[0] = f2bf(v.x); r.u[1] = f2bf(v.y); r.u[2] = f2bf(v.z); r.u[3] = f2bf(v.w);
    *(uint2*)(x_slots + (size_t)slot * C_DIM + threadIdx.x * 4) = r.q;
}

// ---------------- convert+transpose fp32 [R][Cc] -> bf16 [Cc][R]; 64c x 128r tiles ----------------
__global__ __launch_bounds__(256) void convT_kernel(const float* __restrict__ in,
                                                    uint16_t* __restrict__ out, int R, int Cc) {
    __shared__ uint16_t s[128 * 66];
    size_t zb = (size_t)blockIdx.z * (size_t)R * Cc;
    int c0 = blockIdx.x * 64, r0 = blockIdx.y * 128;
    int cx = (threadIdx.x & 15) * 4, ry = threadIdx.x >> 4;
    for (int j = 0; j < 8; j++) {
        int r = ry + j * 16;
        float4 v = *(const float4*)(in + zb + (size_t)(r0 + r) * Cc + c0 + cx);
        uint16_t* p = &s[r * 66 + cx];
        p[0] = f2bf(v.x); p[1] = f2bf(v.y); p[2] = f2bf(v.z); p[3] = f2bf(v.w);
    }
    __syncthreads();
    int oc = threadIdx.x & 63, wseg = threadIdx.x >> 6;  // 4 waves, 32 rows each
    uint16_t tmp[32];
    for (int j = 0; j < 32; j++) tmp[j] = s[(wseg * 32 + j) * 66 + oc];
    uint4* dst = (uint4*)(out + zb + (size_t)(c0 + oc) * R + r0 + wseg * 32);
    dst[0] = *(const uint4*)&tmp[0];
    dst[1] = *(const uint4*)&tmp[8];
    dst[2] = *(const uint4*)&tmp[16];
    dst[3] = *(const uint4*)&tmp[24];
}

// LDS XOR swizzle: staging lane uses global chunk (i&3)^((i>>3)&3); fragment reads use
// slot (lane>>4)^((lane>>1)&3). Conflict-free (verified: SQ_LDS_BANK_CONFLICT=0).
//
// Round-1 change: double-buffered LDS + prefetch-next-K-step issued BEFORE the MFMA
// cluster (T3-minimum 2-phase). One __syncthreads per K-step: its implicit vmcnt(0)
// drain is the depth-1 wait and its lgkmcnt(0) drain protects the WAR on restage.
// Also grid transposed (tile idx fastest) so concurrent blocks reuse one B-tile in L2.

// ---------------- GEMM1: act = swiglu(x_slots @ w_v[e]) ; 128 rows x (64 gate + 64 value) ----------------
__global__ __launch_bounds__(256) void gemm1_kernel(const uint16_t* __restrict__ x_slots,
                                                    const uint16_t* __restrict__ wvT,
                                                    const int* __restrict__ tile_expert,
                                                    const int* __restrict__ tile_row0,
                                                    uint16_t* __restrict__ act) {
    int e = tile_expert[blockIdx.x];
    if (e < 0) return;
    int row0 = tile_row0[blockIdx.x];
    int j = blockIdx.y;  // 0..31, gate cols [j*64, j*64+64)
    __shared__ uint16_t As[2][128 * 32];
    __shared__ uint16_t Bg[2][64 * 32];
    __shared__ uint16_t Bv[2][64 * 32];
    int lane = threadIdx.x & 63, w = threadIdx.x >> 6;
    int wm = w & 1, wn = w >> 1;
    const uint16_t* wvb = wvT + (size_t)e * 4096 * 1024;  // [n=4096][k=1024]

    int sk = (((lane & 3) ^ ((lane >> 3) & 3))) * 8;   // swizzled global k-offset for staging
    int ar = w * 32 + (lane >> 2);            // A row, instr0
    const uint16_t* agp0 = x_slots + (size_t)(row0 + ar) * C_DIM + sk;
    const uint16_t* agp1 = agp0 + (size_t)16 * C_DIM;
    int br = w * 16 + (lane >> 2);            // B row (n) for this wave
    const uint16_t* bgp = wvb + (size_t)(j * 64 + br) * C_DIM + sk;
    const uint16_t* bvp = wvb + (size_t)(2048 + j * 64 + br) * C_DIM + sk;

    int cswz = ((lane >> 4) ^ ((lane >> 1) & 3)) * 8;  // swizzled LDS column for fragment reads

    f32x4 accg[4][2], accv[4][2];
    f32x4 z4 = {0.f, 0.f, 0.f, 0.f};
    for (int mf = 0; mf < 4; mf++)
        for (int nf = 0; nf < 2; nf++) { accg[mf][nf] = z4; accv[mf][nf] = z4; }

#define G1_STAGE(b, ko)                               \
    do {                                              \
        GLL16(agp0 + (ko), &As[b][w * 1024]);         \
        GLL16(agp1 + (ko), &As[b][w * 1024 + 512]);   \
        GLL16(bgp + (ko), &Bg[b][w * 512]);           \
        GLL16(bvp + (ko), &Bv[b][w * 512]);           \
    } while (0)

#define G1_COMPUTE(b)                                                                           \
    do {                                                                                        \
        s16x8 af[4], bg[2], bv[2];                                                              \
        for (int mf = 0; mf < 4; mf++)                                                          \
            af[mf] = *(const s16x8*)&As[b][(wm * 64 + mf * 16 + (lane & 15)) * 32 + cswz];      \
        for (int nf = 0; nf < 2; nf++) {                                                        \
            bg[nf] = *(const s16x8*)&Bg[b][(wn * 32 + nf * 16 + (lane & 15)) * 32 + cswz];      \
            bv[nf] = *(const s16x8*)&Bv[b][(wn * 32 + nf * 16 + (lane & 15)) * 32 + cswz];      \
        }                                                                                       \
        for (int mf = 0; mf < 4; mf++)                                                          \
            for (int nf = 0; nf < 2; nf++) {                                                    \
                accg[mf][nf] = __builtin_amdgcn_mfma_f32_16x16x32_bf16(af[mf], bg[nf], accg[mf][nf], 0, 0, 0); \
                accv[mf][nf] = __builtin_amdgcn_mfma_f32_16x16x32_bf16(af[mf], bv[nf], accv[mf][nf], 0, 0, 0); \
            }                                                                                   \
    } while (0)

    G1_STAGE(0, 0);
    __syncthreads();
    int cur = 0;
    for (int kt = 0; kt < 31; ++kt) {
        G1_STAGE(cur ^ 1, (kt + 1) * 32);   // issue next-tile loads BEFORE compute
        G1_COMPUTE(cur);
        __syncthreads();                     // vmcnt(0)+lgkmcnt(0) drain + barrier
        cur ^= 1;
    }
    G1_COMPUTE(cur);

    for (int mf = 0; mf < 4; mf++)
        for (int nf = 0; nf < 2; nf++)
            for (int r = 0; r < 4; r++) {
                int row = row0 + wm * 64 + mf * 16 + (lane >> 4) * 4 + r;
                int col = j * 64 + wn * 32 + nf * 16 + (lane & 15);
                float g = accg[mf][nf][r], v = accv[mf][nf][r];
                float a = g * v / (1.f + __expf(-g));  // silu(g)*v
                act[(size_t)row * F_DIM + col] = f2bf(a);
            }
}

// ---------------- GEMM2: eo[slot] = weight * (act @ c_proj[e]) ; 128x128 tile, PLAIN bf16 stores ----------------
__global__ __launch_bounds__(256) void gemm2_kernel(const uint16_t* __restrict__ act,
                                                    const uint16_t* __restrict__ cpT,
                                                    const int* __restrict__ tile_expert,
                                                    const int* __restrict__ tile_row0,
                                                    const int* __restrict__ slot_map,
                                                    const float* __restrict__ slot_w,
                                                    uint16_t* __restrict__ eo) {
    int e = tile_expert[blockIdx.x];
    if (e < 0) return;
    int row0 = tile_row0[blockIdx.x];
    int cb = blockIdx.y * 128;
    __shared__ uint16_t As[2][128 * 32];
    __shared__ uint16_t Bs[2][128 * 32];
    int lane = threadIdx.x & 63, w = threadIdx.x >> 6;
    int wm = w & 1, wn = w >> 1;
    const uint16_t* cpb = cpT + (size_t)e * 1024 * 2048;  // [n=1024][k=2048]

    int sk = (((lane & 3) ^ ((lane >> 3) & 3))) * 8;
    int ar = w * 32 + (lane >> 2);
    const uint16_t* agp0 = act + (size_t)(row0 + ar) * F_DIM + sk;
    const uint16_t* agp1 = agp0 + (size_t)16 * F_DIM;
    const uint16_t* bgp0 = cpb + (size_t)(cb + ar) * F_DIM + sk;
    const uint16_t* bgp1 = bgp0 + (size_t)16 * F_DIM;

    int cswz = ((lane >> 4) ^ ((lane >> 1) & 3)) * 8;

    f32x4 acc[4][4];
    f32x4 z4 = {0.f, 0.f, 0.f, 0.f};
    for (int mf = 0; mf < 4; mf++)
        for (int nf = 0; nf < 4; nf++) acc[mf][nf] = z4;

#define G2_STAGE(b, ko)                               \
    do {                                              \
        GLL16(agp0 + (ko), &As[b][w * 1024]);         \
        GLL16(agp1 + (ko), &As[b][w * 1024 + 512]);   \
        GLL16(bgp0 + (ko), &Bs[b][w * 1024]);         \
        GLL16(bgp1 + (ko), &Bs[b][w * 1024 + 512]);   \
    } while (0)

#define G2_COMPUTE(b)                                                                           \
    do {                                                                                        \
        s16x8 af[4], bf[4];                                                                     \
        for (int mf = 0; mf < 4; mf++)                                                          \
            af[mf] = *(const s16x8*)&As[b][(wm * 64 + mf * 16 + (lane & 15)) * 32 + cswz];      \
        for (int nf = 0; nf < 4; nf++)                                                          \
            bf[nf] = *(const s16x8*)&Bs[b][(wn * 64 + nf * 16 + (lane & 15)) * 32 + cswz];      \
        for (int mf = 0; mf < 4; mf++)                                                          \
            for (int nf = 0; nf < 4; nf++)                                                      \
                acc[mf][nf] = __builtin_amdgcn_mfma_f32_16x16x32_bf16(af[mf], bf[nf], acc[mf][nf], 0, 0, 0); \
    } while (0)

    G2_STAGE(0, 0);
    __syncthreads();
    int cur = 0;
    for (int kt = 0; kt < 63; ++kt) {
        G2_STAGE(cur ^ 1, (kt + 1) * 32);
        G2_COMPUTE(cur);
        __syncthreads();
        cur ^= 1;
    }
    G2_COMPUTE(cur);

    for (int mf = 0; mf < 4; mf++)
        for (int r = 0; r < 4; r++) {
            int slotr = row0 + wm * 64 + mf * 16 + (lane >> 4) * 4 + r;
            int t2k = slot_map[slotr];
            if (t2k < 0) continue;  // padding row: skip (eo row never read)
            float wgt = slot_w[slotr];
            for (int nf = 0; nf < 4; nf++) {
                int col = cb + wn * 64 + nf * 16 + (lane & 15);
                eo[(size_t)slotr * C_DIM + col] = f2bf(wgt * acc[mf][nf][r]);
            }
        }
}

// ---------------- combine: out[t] = eo[slot0] + eo[slot1] (weights pre-applied) ----------------
__global__ void combine_kernel(const uint16_t* __restrict__ eo, const int* __restrict__ tok_slot,
                               float* __restrict__ out) {
    int t = blockIdx.x;
    int s0 = tok_slot[2 * t], s1 = tok_slot[2 * t + 1];
    int c = threadIdx.x * 4;
    uint2 a = *(const uint2*)(eo + (size_t)s0 * C_DIM + c);
    uint2 b = *(const uint2*)(eo + (size_t)s1 * C_DIM + c);
    float4 o;
    o.x = bf2f((uint16_t)(a.x & 0xffff)) + bf2f((uint16_t)(b.x & 0xffff));
    o.y = bf2f((uint16_t)(a.x >> 16)) + bf2f((uint16_t)(b.x >> 16));
    o.z = bf2f((uint16_t)(a.y & 0xffff)) + bf2f((uint16_t)(b.y & 0xffff));
    o.w = bf2f((uint16_t)(a.y >> 16)) + bf2f((uint16_t)(b.y >> 16));
    *(float4*)(out + (size_t)t * C_DIM + c) = o;
}

extern "C" void kernel_launch(void* const* d_in, const int* in_sizes, int n_in,
                              void* d_out, int out_size, void* d_ws, size_t ws_size,
                              hipStream_t stream) {
    (void)in_sizes; (void)n_in; (void)out_size; (void)ws_size;
    const float* x = (const float*)d_in[0];
    const float* rw = (const float*)d_in[1];
    const float* wv = (const float*)d_in[2];
    const float* cp = (const float*)d_in[3];
    float* out = (float*)d_out;

    char* ws = (char*)d_ws;
    size_t off = 0;
    auto alloc = [&](size_t sz) -> void* {
        off = (off + 255) & ~(size_t)255;
        void* p = ws + off;
        off += sz;
        return p;
    };
    uint16_t* wvT = (uint16_t*)alloc((size_t)E_NUM * 4096 * 1024 * 2);   // 64 MB
    uint16_t* cpT = (uint16_t*)alloc((size_t)E_NUM * 1024 * 2048 * 2);   // 32 MB
    uint16_t* x_slots = (uint16_t*)alloc((size_t)SMAX * C_DIM * 2);      // ~19 MB
    uint16_t* act = (uint16_t*)alloc((size_t)SMAX * F_DIM * 2);          // ~38 MB
    uint16_t* eo = (uint16_t*)alloc((size_t)SMAX * C_DIM * 2);           // ~19 MB
    float* psum_part = (float*)alloc((size_t)RBLK * E_NUM * 4);
    int* cnt_part = (int*)alloc((size_t)RBLK * E_NUM * 4);
    int* count2 = (int*)alloc(E_NUM * 4);
    int* offsets = (int*)alloc((E_NUM + 1) * 4);
    int* tile_expert = (int*)alloc(TILES_MAX * 4);
    int* tile_row0 = (int*)alloc(TILES_MAX * 4);
    int* topk_idx = (int*)alloc((size_t)N_TOK * 2 * 4);
    float* topk_w = (float*)alloc((size_t)N_TOK * 2 * 4);
    int* slot_map = (int*)alloc((size_t)SMAX * 4);
    float* slot_w = (float*)alloc((size_t)SMAX * 4);
    int* tok_slot = (int*)alloc((size_t)N_TOK * 2 * 4);

    hipMemsetAsync(count2, 0, E_NUM * 4, stream);
    hipMemsetAsync(slot_map, 0xFF, (size_t)SMAX * 4, stream);  // -1 => padding

    router_kernel<<<RBLK, 256, 0, stream>>>(x, rw, topk_idx, topk_w, psum_part, cnt_part);
    reduce_plan_kernel<<<1, 256, 0, stream>>>(psum_part, cnt_part, offsets, tile_expert, tile_row0,
                                              out + (size_t)N_TOK * C_DIM);
    assign_kernel<<<N_TOK * 2 / 256, 256, 0, stream>>>(topk_idx, topk_w, offsets, count2,
                                                       slot_map, slot_w, tok_slot);
    gather_kernel<<<SMAX, 256, 0, stream>>>(x, slot_map, x_slots);
    convT_kernel<<<dim3(4096 / 64, 1024 / 128, E_NUM), 256, 0, stream>>>(wv, wvT, 1024, 4096);
    convT_kernel<<<dim3(1024 / 64, 2048 / 128, E_NUM), 256, 0, stream>>>(cp, cpT, 2048, 1024);
    gemm1_kernel<<<dim3(TILES_MAX, 32), 256, 0, stream>>>(x_slots, wvT, tile_expert, tile_row0, act);
    gemm2_kernel<<<dim3(TILES_MAX, 8), 256, 0, stream>>>(act, cpT, tile_expert, tile_row0,
                                                         slot_map, slot_w, eo);
    combine_kernel<<<N_TOK, 256, 0, stream>>>(eo, tok_slot, out);
}

// Round 2
// 489.343 us; speedup vs baseline: 1.0589x; 1.0589x over previous
//
#include <hip/hip_runtime.h>
#include <hip/hip_bf16.h>
#include <stdint.h>

#define N_TOK 4096
#define C_DIM 1024
#define F_DIM 2048
#define E_NUM 8
#define SMAX 9216       // 72 tiles * 128 rows: max padded slot count
#define TILES_MAX 72
#define RBLK 1024       // router blocks (4 tokens each)

typedef __attribute__((ext_vector_type(4))) float f32x4;
typedef __attribute__((ext_vector_type(8))) short s16x8;

__device__ __forceinline__ uint16_t f2bf(float f) {
    unsigned x;
    __builtin_memcpy(&x, &f, 4);
    unsigned r = (x + 0x7fffu + ((x >> 16) & 1u)) >> 16;  // RNE
    return (uint16_t)r;
}
__device__ __forceinline__ float bf2f(uint16_t u) {
    unsigned v = (unsigned)u << 16;
    float f;
    __builtin_memcpy(&f, &v, 4);
    return f;
}

#define GLL16(gp, lp)                                                                  \
    __builtin_amdgcn_global_load_lds((const __attribute__((address_space(1))) unsigned int*)(gp), \
                                     (__attribute__((address_space(3))) unsigned int*)(lp), 16, 0, 0)

// ---------------- router: fp32 logits -> softmax -> top2; LDS-aggregated partials ----------------
__global__ void router_kernel(const float* __restrict__ x, const float* __restrict__ rw,
                              int* __restrict__ topk_idx, float* __restrict__ topk_w,
                              float* __restrict__ psum_part, int* __restrict__ cnt_part) {
    __shared__ float s_p[E_NUM];
    __shared__ int s_c[E_NUM];
    if (threadIdx.x < E_NUM) { s_p[threadIdx.x] = 0.f; s_c[threadIdx.x] = 0; }
    __syncthreads();

    int lane = threadIdx.x & 63;
    int wv = threadIdx.x >> 6;
    int t = blockIdx.x * 4 + wv;

    const float* xr = x + (size_t)t * C_DIM + lane * 16;
    float xs[16];
    for (int i = 0; i < 4; i++) *(float4*)&xs[i * 4] = *(const float4*)(xr + i * 4);

    float acc[E_NUM];
    for (int e = 0; e < E_NUM; e++) {
        const float* wr = rw + e * C_DIM + lane * 16;
        float s = 0.f;
        for (int i = 0; i < 4; i++) {
            float4 v = *(const float4*)(wr + i * 4);
            s += xs[i * 4] * v.x + xs[i * 4 + 1] * v.y + xs[i * 4 + 2] * v.z + xs[i * 4 + 3] * v.w;
        }
        acc[e] = s;
    }
    for (int off = 32; off > 0; off >>= 1)
        for (int e = 0; e < E_NUM; e++) acc[e] += __shfl_down(acc[e], off, 64);

    if (lane == 0) {
        float m = acc[0];
        for (int e = 1; e < E_NUM; e++) m = fmaxf(m, acc[e]);
        float p[E_NUM], s = 0.f;
        for (int e = 0; e < E_NUM; e++) { p[e] = __expf(acc[e] - m); s += p[e]; }
        float inv = 1.f / s;
        for (int e = 0; e < E_NUM; e++) { p[e] *= inv; atomicAdd(&s_p[e], p[e]); }  // LDS atomic
        int i0 = 0;
        for (int e = 1; e < E_NUM; e++) if (p[e] > p[i0]) i0 = e;         // ties -> lowest idx
        int i1 = (i0 == 0) ? 1 : 0;
        for (int e = 0; e < E_NUM; e++) if (e != i0 && p[e] > p[i1]) i1 = e;
        float w0 = p[i0], w1 = p[i1], wsum = w0 + w1;
        topk_idx[t * 2] = i0; topk_idx[t * 2 + 1] = i1;
        topk_w[t * 2] = w0 / wsum; topk_w[t * 2 + 1] = w1 / wsum;
        atomicAdd(&s_c[i0], 1); atomicAdd(&s_c[i1], 1);                   // LDS atomic
    }
    __syncthreads();
    if (threadIdx.x < E_NUM) {
        psum_part[blockIdx.x * E_NUM + threadIdx.x] = s_p[threadIdx.x];
        cnt_part[blockIdx.x * E_NUM + threadIdx.x] = s_c[threadIdx.x];
    }
}

// ---------------- reduce partials -> counts/psum; plan offsets+tiles; aux loss ----------------
__global__ void reduce_plan_kernel(const float* __restrict__ psum_part, const int* __restrict__ cnt_part,
                                   int* __restrict__ offsets, int* __restrict__ tile_expert,
                                   int* __restrict__ tile_row0, float* __restrict__ aux_out) {
    __shared__ float sp[256];
    __shared__ int sc[256];
    __shared__ int s_count[E_NUM];
    __shared__ float s_psum[E_NUM];
    int e = threadIdx.x >> 5, i = threadIdx.x & 31;
    float fp = 0.f; int c = 0;
    for (int j = i; j < RBLK; j += 32) { fp += psum_part[j * E_NUM + e]; c += cnt_part[j * E_NUM + e]; }
    sp[threadIdx.x] = fp; sc[threadIdx.x] = c;
    __syncthreads();
    for (int s = 16; s > 0; s >>= 1) {
        if (i < s) { sp[threadIdx.x] += sp[threadIdx.x + s]; sc[threadIdx.x] += sc[threadIdx.x + s]; }
        __syncthreads();
    }
    if (i == 0) { s_count[e] = sc[threadIdx.x]; s_psum[e] = sp[threadIdx.x]; }
    __syncthreads();
    if (threadIdx.x == 0) {
        int off = 0, t = 0;
        for (int ee = 0; ee < E_NUM; ee++) {
            offsets[ee] = off;
            int n = s_count[ee];
            int nt = (n + 127) >> 7;
            for (int k = 0; k < nt; k++) { tile_expert[t] = ee; tile_row0[t] = off + k * 128; t++; }
            off += nt * 128;
        }
        offsets[E_NUM] = off;
        for (; t < TILES_MAX; t++) tile_expert[t] = -1;
        float s = 0.f;
        for (int ee = 0; ee < E_NUM; ee++) { float a = s_psum[ee] * (1.f / N_TOK); s += a * a; }
        aux_out[0] = 8.f * s;
    }
}

// ---------------- assign: block-aggregated slot reservation + inverse map ----------------
__global__ void assign_kernel(const int* __restrict__ topk_idx, const float* __restrict__ topk_w,
                              const int* __restrict__ offsets, int* __restrict__ count2,
                              int* __restrict__ slot_map, float* __restrict__ slot_w,
                              int* __restrict__ tok_slot) {
    __shared__ int h[E_NUM];
    __shared__ int base[E_NUM];
    if (threadIdx.x < E_NUM) h[threadIdx.x] = 0;
    __syncthreads();
    int item = blockIdx.x * 256 + threadIdx.x;
    int e = topk_idx[item];
    int rank = atomicAdd(&h[e], 1);         // LDS atomic
    __syncthreads();
    if (threadIdx.x < E_NUM)
        base[threadIdx.x] = offsets[threadIdx.x] + atomicAdd(&count2[threadIdx.x], h[threadIdx.x]);
    __syncthreads();
    int slot = base[e] + rank;
    slot_map[slot] = item;
    slot_w[slot] = topk_w[item];
    tok_slot[item] = slot;
}

// ---------------- gather: copy+convert x rows (fp32 -> bf16) into slot space ----------------
__global__ void gather_kernel(const float* __restrict__ x, const int* __restrict__ slot_map,
                              uint16_t* __restrict__ x_slots) {
    int slot = blockIdx.x;
    int item = slot_map[slot];
    if (item < 0) return;  // padding row: leave poison (tiny denormals, harmless)
    int t = item >> 1;
    float4 v = *(const float4*)(x + (size_t)t * C_DIM + threadIdx.x * 4);
    union { uint16_t u[4]; uint2 q; } r;
    r.u[0] = f2bf(v.x); r.u[1] = f2bf(v.y); r.u[2] = f2bf(v.z); r.u[3] = f2bf(v.w);
    *(uint2*)(x_slots + (size_t)slot * C_DIM + threadIdx.x * 4) = r.q;
}

// ---------------- convert+transpose fp32 [R][Cc] -> bf16 [Cc][R]; 64c x 128r tiles ----------------
__global__ __launch_bounds__(256) void convT_kernel(const float* __restrict__ in,
                                                    uint16_t* __restrict__ out, int R, int Cc) {
    __shared__ uint16_t s[128 * 66];
    size_t zb = (size_t)blockIdx.z * (size_t)R * Cc;
    int c0 = blockIdx.x * 64, r0 = blockIdx.y * 128;
    int cx = (threadIdx.x & 15) * 4, ry = threadIdx.x >> 4;
    for (int j = 0; j < 8; j++) {
        int r = ry + j * 16;
        float4 v = *(const float4*)(in + zb + (size_t)(r0 + r) * Cc + c0 + cx);
        uint16_t* p = &s[r * 66 + cx];
        p[0] = f2bf(v.x); p[1] = f2bf(v.y); p[2] = f2bf(v.z); p[3] = f2bf(v.w);
    }
    __syncthreads();
    int oc = threadIdx.x & 63, wseg = threadIdx.x >> 6;  // 4 waves, 32 rows each
    uint16_t tmp[32];
    for (int j = 0; j < 32; j++) tmp[j] = s[(wseg * 32 + j) * 66 + oc];
    uint4* dst = (uint4*)(out + zb + (size_t)(c0 + oc) * R + r0 + wseg * 32);
    dst[0] = *(const uint4*)&tmp[0];
    dst[1] = *(const uint4*)&tmp[8];
    dst[2] = *(const uint4*)&tmp[16];
    dst[3] = *(const uint4*)&tmp[24];
}

// LDS XOR swizzle: staging lane uses global chunk (i&3)^((i>>3)&3); fragment reads use
// slot (lane>>4)^((lane>>1)&3). Conflict-free (verified: SQ_LDS_BANK_CONFLICT=0).
//
// Round-2: grid REVERTED to j-fastest (round-1 tile-fastest grid caused 4x A-refetch,
// FETCH 110->405 MB, HBM-bound at 3.2 TB/s). Double-buffer prefetch KEPT but with
// compile-time buffer indices (2x unrolled K-loop) so the compiler can statically
// disambiguate ds_read src (buf b) from global_load_lds dest (buf b^1) and not insert
// an early vmcnt drain before the fragment reads.

// ---------------- GEMM1: act = swiglu(x_slots @ w_v[e]) ; 128 rows x (64 gate + 64 value) ----------------
__global__ __launch_bounds__(256) void gemm1_kernel(const uint16_t* __restrict__ x_slots,
                                                    const uint16_t* __restrict__ wvT,
                                                    const int* __restrict__ tile_expert,
                                                    const int* __restrict__ tile_row0,
                                                    uint16_t* __restrict__ act) {
    int e = tile_expert[blockIdx.y];
    if (e < 0) return;
    int row0 = tile_row0[blockIdx.y];
    int j = blockIdx.x;  // 0..31, gate cols [j*64, j*64+64)
    __shared__ uint16_t As[2][128 * 32];
    __shared__ uint16_t Bg[2][64 * 32];
    __shared__ uint16_t Bv[2][64 * 32];
    int lane = threadIdx.x & 63, w = threadIdx.x >> 6;
    int wm = w & 1, wn = w >> 1;
    const uint16_t* wvb = wvT + (size_t)e * 4096 * 1024;  // [n=4096][k=1024]

    int sk = (((lane & 3) ^ ((lane >> 3) & 3))) * 8;   // swizzled global k-offset for staging
    int ar = w * 32 + (lane >> 2);            // A row, instr0
    const uint16_t* agp0 = x_slots + (size_t)(row0 + ar) * C_DIM + sk;
    const uint16_t* agp1 = agp0 + (size_t)16 * C_DIM;
    int br = w * 16 + (lane >> 2);            // B row (n) for this wave
    const uint16_t* bgp = wvb + (size_t)(j * 64 + br) * C_DIM + sk;
    const uint16_t* bvp = wvb + (size_t)(2048 + j * 64 + br) * C_DIM + sk;

    int cswz = ((lane >> 4) ^ ((lane >> 1) & 3)) * 8;  // swizzled LDS column for fragment reads

    f32x4 accg[4][2], accv[4][2];
    f32x4 z4 = {0.f, 0.f, 0.f, 0.f};
    for (int mf = 0; mf < 4; mf++)
        for (int nf = 0; nf < 2; nf++) { accg[mf][nf] = z4; accv[mf][nf] = z4; }

#define G1_STAGE(b, ko)                               \
    do {                                              \
        GLL16(agp0 + (ko), &As[b][w * 1024]);         \
        GLL16(agp1 + (ko), &As[b][w * 1024 + 512]);   \
        GLL16(bgp + (ko), &Bg[b][w * 512]);           \
        GLL16(bvp + (ko), &Bv[b][w * 512]);           \
    } while (0)

#define G1_COMPUTE(b)                                                                           \
    do {                                                                                        \
        s16x8 af[4], bg[2], bv[2];                                                              \
        for (int mf = 0; mf < 4; mf++)                                                          \
            af[mf] = *(const s16x8*)&As[b][(wm * 64 + mf * 16 + (lane & 15)) * 32 + cswz];      \
        for (int nf = 0; nf < 2; nf++) {                                                        \
            bg[nf] = *(const s16x8*)&Bg[b][(wn * 32 + nf * 16 + (lane & 15)) * 32 + cswz];      \
            bv[nf] = *(const s16x8*)&Bv[b][(wn * 32 + nf * 16 + (lane & 15)) * 32 + cswz];      \
        }                                                                                       \
        for (int mf = 0; mf < 4; mf++)                                                          \
            for (int nf = 0; nf < 2; nf++) {                                                    \
                accg[mf][nf] = __builtin_amdgcn_mfma_f32_16x16x32_bf16(af[mf], bg[nf], accg[mf][nf], 0, 0, 0); \
                accv[mf][nf] = __builtin_amdgcn_mfma_f32_16x16x32_bf16(af[mf], bv[nf], accv[mf][nf], 0, 0, 0); \
            }                                                                                   \
    } while (0)

    G1_STAGE(0, 0);
    __syncthreads();
    // 32 K-steps, unrolled x2 with STATIC buffer indices.
    for (int kt = 0; kt < 32; kt += 2) {
        G1_STAGE(1, (kt + 1) * 32);          // prefetch next into buf1 BEFORE compute
        G1_COMPUTE(0);
        __syncthreads();                     // vmcnt(0)+lgkmcnt(0): buf1 ready, buf0 free
        if (kt + 2 < 32) G1_STAGE(0, (kt + 2) * 32);
        G1_COMPUTE(1);
        __syncthreads();
    }

    for (int mf = 0; mf < 4; mf++)
        for (int nf = 0; nf < 2; nf++)
            for (int r = 0; r < 4; r++) {
                int row = row0 + wm * 64 + mf * 16 + (lane >> 4) * 4 + r;
                int col = j * 64 + wn * 32 + nf * 16 + (lane & 15);
                float g = accg[mf][nf][r], v = accv[mf][nf][r];
                float a = g * v / (1.f + __expf(-g));  // silu(g)*v
                act[(size_t)row * F_DIM + col] = f2bf(a);
            }
}

// ---------------- GEMM2: eo[slot] = weight * (act @ c_proj[e]) ; 128x128 tile, PLAIN bf16 stores ----------------
__global__ __launch_bounds__(256) void gemm2_kernel(const uint16_t* __restrict__ act,
                                                    const uint16_t* __restrict__ cpT,
                                                    const int* __restrict__ tile_expert,
                                                    const int* __restrict__ tile_row0,
                                                    const int* __restrict__ slot_map,
                                                    const float* __restrict__ slot_w,
                                                    uint16_t* __restrict__ eo) {
    int e = tile_expert[blockIdx.y];
    if (e < 0) return;
    int row0 = tile_row0[blockIdx.y];
    int cb = blockIdx.x * 128;
    __shared__ uint16_t As[2][128 * 32];
    __shared__ uint16_t Bs[2][128 * 32];
    int lane = threadIdx.x & 63, w = threadIdx.x >> 6;
    int wm = w & 1, wn = w >> 1;
    const uint16_t* cpb = cpT + (size_t)e * 1024 * 2048;  // [n=1024][k=2048]

    int sk = (((lane & 3) ^ ((lane >> 3) & 3))) * 8;
    int ar = w * 32 + (lane >> 2);
    const uint16_t* agp0 = act + (size_t)(row0 + ar) * F_DIM + sk;
    const uint16_t* agp1 = agp0 + (size_t)16 * F_DIM;
    const uint16_t* bgp0 = cpb + (size_t)(cb + ar) * F_DIM + sk;
    const uint16_t* bgp1 = bgp0 + (size_t)16 * F_DIM;

    int cswz = ((lane >> 4) ^ ((lane >> 1) & 3)) * 8;

    f32x4 acc[4][4];
    f32x4 z4 = {0.f, 0.f, 0.f, 0.f};
    for (int mf = 0; mf < 4; mf++)
        for (int nf = 0; nf < 4; nf++) acc[mf][nf] = z4;

#define G2_STAGE(b, ko)                               \
    do {                                              \
        GLL16(agp0 + (ko), &As[b][w * 1024]);         \
        GLL16(agp1 + (ko), &As[b][w * 1024 + 512]);   \
        GLL16(bgp0 + (ko), &Bs[b][w * 1024]);         \
        GLL16(bgp1 + (ko), &Bs[b][w * 1024 + 512]);   \
    } while (0)

#define G2_COMPUTE(b)                                                                           \
    do {                                                                                        \
        s16x8 af[4], bf[4];                                                                     \
        for (int mf = 0; mf < 4; mf++)                                                          \
            af[mf] = *(const s16x8*)&As[b][(wm * 64 + mf * 16 + (lane & 15)) * 32 + cswz];      \
        for (int nf = 0; nf < 4; nf++)                                                          \
            bf[nf] = *(const s16x8*)&Bs[b][(wn * 64 + nf * 16 + (lane & 15)) * 32 + cswz];      \
        for (int mf = 0; mf < 4; mf++)                                                          \
            for (int nf = 0; nf < 4; nf++)                                                      \
                acc[mf][nf] = __builtin_amdgcn_mfma_f32_16x16x32_bf16(af[mf], bf[nf], acc[mf][nf], 0, 0, 0); \
    } while (0)

    G2_STAGE(0, 0);
    __syncthreads();
    for (int kt = 0; kt < 64; kt += 2) {
        G2_STAGE(1, (kt + 1) * 32);
        G2_COMPUTE(0);
        __syncthreads();
        if (kt + 2 < 64) G2_STAGE(0, (kt + 2) * 32);
        G2_COMPUTE(1);
        __syncthreads();
    }

    for (int mf = 0; mf < 4; mf++)
        for (int r = 0; r < 4; r++) {
            int slotr = row0 + wm * 64 + mf * 16 + (lane >> 4) * 4 + r;
            int t2k = slot_map[slotr];
            if (t2k < 0) continue;  // padding row: skip (eo row never read)
            float wgt = slot_w[slotr];
            for (int nf = 0; nf < 4; nf++) {
                int col = cb + wn * 64 + nf * 16 + (lane & 15);
                eo[(size_t)slotr * C_DIM + col] = f2bf(wgt * acc[mf][nf][r]);
            }
        }
}

// ---------------- combine: out[t] = eo[slot0] + eo[slot1] (weights pre-applied) ----------------
__global__ void combine_kernel(const uint16_t* __restrict__ eo, const int* __restrict__ tok_slot,
                               float* __restrict__ out) {
    int t = blockIdx.x;
    int s0 = tok_slot[2 * t], s1 = tok_slot[2 * t + 1];
    int c = threadIdx.x * 4;
    uint2 a = *(const uint2*)(eo + (size_t)s0 * C_DIM + c);
    uint2 b = *(const uint2*)(eo + (size_t)s1 * C_DIM + c);
    float4 o;
    o.x = bf2f((uint16_t)(a.x & 0xffff)) + bf2f((uint16_t)(b.x & 0xffff));
    o.y = bf2f((uint16_t)(a.x >> 16)) + bf2f((uint16_t)(b.x >> 16));
    o.z = bf2f((uint16_t)(a.y & 0xffff)) + bf2f((uint16_t)(b.y & 0xffff));
    o.w = bf2f((uint16_t)(a.y >> 16)) + bf2f((uint16_t)(b.y >> 16));
    *(float4*)(out + (size_t)t * C_DIM + c) = o;
}

extern "C" void kernel_launch(void* const* d_in, const int* in_sizes, int n_in,
                              void* d_out, int out_size, void* d_ws, size_t ws_size,
                              hipStream_t stream) {
    (void)in_sizes; (void)n_in; (void)out_size; (void)ws_size;
    const float* x = (const float*)d_in[0];
    const float* rw = (const float*)d_in[1];
    const float* wv = (const float*)d_in[2];
    const float* cp = (const float*)d_in[3];
    float* out = (float*)d_out;

    char* ws = (char*)d_ws;
    size_t off = 0;
    auto alloc = [&](size_t sz) -> void* {
        off = (off + 255) & ~(size_t)255;
        void* p = ws + off;
        off += sz;
        return p;
    };
    uint16_t* wvT = (uint16_t*)alloc((size_t)E_NUM * 4096 * 1024 * 2);   // 64 MB
    uint16_t* cpT = (uint16_t*)alloc((size_t)E_NUM * 1024 * 2048 * 2);   // 32 MB
    uint16_t* x_slots = (uint16_t*)alloc((size_t)SMAX * C_DIM * 2);      // ~19 MB
    uint16_t* act = (uint16_t*)alloc((size_t)SMAX * F_DIM * 2);          // ~38 MB
    uint16_t* eo = (uint16_t*)alloc((size_t)SMAX * C_DIM * 2);           // ~19 MB
    float* psum_part = (float*)alloc((size_t)RBLK * E_NUM * 4);
    int* cnt_part = (int*)alloc((size_t)RBLK * E_NUM * 4);
    int* count2 = (int*)alloc(E_NUM * 4);
    int* offsets = (int*)alloc((E_NUM + 1) * 4);
    int* tile_expert = (int*)alloc(TILES_MAX * 4);
    int* tile_row0 = (int*)alloc(TILES_MAX * 4);
    int* topk_idx = (int*)alloc((size_t)N_TOK * 2 * 4);
    float* topk_w = (float*)alloc((size_t)N_TOK * 2 * 4);
    int* slot_map = (int*)alloc((size_t)SMAX * 4);
    float* slot_w = (float*)alloc((size_t)SMAX * 4);
    int* tok_slot = (int*)alloc((size_t)N_TOK * 2 * 4);

    hipMemsetAsync(count2, 0, E_NUM * 4, stream);
    hipMemsetAsync(slot_map, 0xFF, (size_t)SMAX * 4, stream);  // -1 => padding

    router_kernel<<<RBLK, 256, 0, stream>>>(x, rw, topk_idx, topk_w, psum_part, cnt_part);
    reduce_plan_kernel<<<1, 256, 0, stream>>>(psum_part, cnt_part, offsets, tile_expert, tile_row0,
                                              out + (size_t)N_TOK * C_DIM);
    assign_kernel<<<N_TOK * 2 / 256, 256, 0, stream>>>(topk_idx, topk_w, offsets, count2,
                                                       slot_map, slot_w, tok_slot);
    gather_kernel<<<SMAX, 256, 0, stream>>>(x, slot_map, x_slots);
    convT_kernel<<<dim3(4096 / 64, 1024 / 128, E_NUM), 256, 0, stream>>>(wv, wvT, 1024, 4096);
    convT_kernel<<<dim3(1024 / 64, 2048 / 128, E_NUM), 256, 0, stream>>>(cp, cpT, 2048, 1024);
    gemm1_kernel<<<dim3(32, TILES_MAX), 256, 0, stream>>>(x_slots, wvT, tile_expert, tile_row0, act);
    gemm2_kernel<<<dim3(8, TILES_MAX), 256, 0, stream>>>(act, cpT, tile_expert, tile_row0,
                                                         slot_map, slot_w, eo);
    combine_kernel<<<N_TOK, 256, 0, stream>>>(eo, tok_slot, out);
}

// Round 3
// 486.795 us; speedup vs baseline: 1.0644x; 1.0052x over previous
//
#include <hip/hip_runtime.h>
#include <hip/hip_bf16.h>
#include <stdint.h>

#define N_TOK 4096
#define C_DIM 1024
#define F_DIM 2048
#define E_NUM 8
#define SMAX 10240      // 40 tiles * 256 rows: max padded slot count (256-granular)
#define T256_MAX 40
#define T128_MAX 72
#define RBLK 1024       // router blocks (4 tokens each)

typedef __attribute__((ext_vector_type(4))) float f32x4;
typedef __attribute__((ext_vector_type(8))) short s16x8;

__device__ __forceinline__ uint16_t f2bf(float f) {
    unsigned x;
    __builtin_memcpy(&x, &f, 4);
    unsigned r = (x + 0x7fffu + ((x >> 16) & 1u)) >> 16;  // RNE
    return (uint16_t)r;
}
__device__ __forceinline__ float bf2f(uint16_t u) {
    unsigned v = (unsigned)u << 16;
    float f;
    __builtin_memcpy(&f, &v, 4);
    return f;
}

#define GLL16(gp, lp)                                                                  \
    __builtin_amdgcn_global_load_lds((const __attribute__((address_space(1))) unsigned int*)(gp), \
                                     (__attribute__((address_space(3))) unsigned int*)(lp), 16, 0, 0)

// ---------------- router: fp32 logits -> softmax -> top2; LDS-aggregated partials ----------------
__global__ void router_kernel(const float* __restrict__ x, const float* __restrict__ rw,
                              int* __restrict__ topk_idx, float* __restrict__ topk_w,
                              float* __restrict__ psum_part, int* __restrict__ cnt_part) {
    __shared__ float s_p[E_NUM];
    __shared__ int s_c[E_NUM];
    if (threadIdx.x < E_NUM) { s_p[threadIdx.x] = 0.f; s_c[threadIdx.x] = 0; }
    __syncthreads();

    int lane = threadIdx.x & 63;
    int wv = threadIdx.x >> 6;
    int t = blockIdx.x * 4 + wv;

    const float* xr = x + (size_t)t * C_DIM + lane * 16;
    float xs[16];
    for (int i = 0; i < 4; i++) *(float4*)&xs[i * 4] = *(const float4*)(xr + i * 4);

    float acc[E_NUM];
    for (int e = 0; e < E_NUM; e++) {
        const float* wr = rw + e * C_DIM + lane * 16;
        float s = 0.f;
        for (int i = 0; i < 4; i++) {
            float4 v = *(const float4*)(wr + i * 4);
            s += xs[i * 4] * v.x + xs[i * 4 + 1] * v.y + xs[i * 4 + 2] * v.z + xs[i * 4 + 3] * v.w;
        }
        acc[e] = s;
    }
    for (int off = 32; off > 0; off >>= 1)
        for (int e = 0; e < E_NUM; e++) acc[e] += __shfl_down(acc[e], off, 64);

    if (lane == 0) {
        float m = acc[0];
        for (int e = 1; e < E_NUM; e++) m = fmaxf(m, acc[e]);
        float p[E_NUM], s = 0.f;
        for (int e = 0; e < E_NUM; e++) { p[e] = __expf(acc[e] - m); s += p[e]; }
        float inv = 1.f / s;
        for (int e = 0; e < E_NUM; e++) { p[e] *= inv; atomicAdd(&s_p[e], p[e]); }  // LDS atomic
        int i0 = 0;
        for (int e = 1; e < E_NUM; e++) if (p[e] > p[i0]) i0 = e;         // ties -> lowest idx
        int i1 = (i0 == 0) ? 1 : 0;
        for (int e = 0; e < E_NUM; e++) if (e != i0 && p[e] > p[i1]) i1 = e;
        float w0 = p[i0], w1 = p[i1], wsum = w0 + w1;
        topk_idx[t * 2] = i0; topk_idx[t * 2 + 1] = i1;
        topk_w[t * 2] = w0 / wsum; topk_w[t * 2 + 1] = w1 / wsum;
        atomicAdd(&s_c[i0], 1); atomicAdd(&s_c[i1], 1);                   // LDS atomic
    }
    __syncthreads();
    if (threadIdx.x < E_NUM) {
        psum_part[blockIdx.x * E_NUM + threadIdx.x] = s_p[threadIdx.x];
        cnt_part[blockIdx.x * E_NUM + threadIdx.x] = s_c[threadIdx.x];
    }
}

// ---------------- reduce partials -> counts/psum; plan 256-tiles (gemm1) + 128-tiles (gemm2) ----------------
__global__ void reduce_plan_kernel(const float* __restrict__ psum_part, const int* __restrict__ cnt_part,
                                   int* __restrict__ offsets, int* __restrict__ tile_e256,
                                   int* __restrict__ tile_r256, int* __restrict__ tile_e128,
                                   int* __restrict__ tile_r128, float* __restrict__ aux_out) {
    __shared__ float sp[256];
    __shared__ int sc[256];
    __shared__ int s_count[E_NUM];
    __shared__ float s_psum[E_NUM];
    int e = threadIdx.x >> 5, i = threadIdx.x & 31;
    float fp = 0.f; int c = 0;
    for (int j = i; j < RBLK; j += 32) { fp += psum_part[j * E_NUM + e]; c += cnt_part[j * E_NUM + e]; }
    sp[threadIdx.x] = fp; sc[threadIdx.x] = c;
    __syncthreads();
    for (int s = 16; s > 0; s >>= 1) {
        if (i < s) { sp[threadIdx.x] += sp[threadIdx.x + s]; sc[threadIdx.x] += sc[threadIdx.x + s]; }
        __syncthreads();
    }
    if (i == 0) { s_count[e] = sc[threadIdx.x]; s_psum[e] = sp[threadIdx.x]; }
    __syncthreads();
    if (threadIdx.x == 0) {
        int off = 0, t2 = 0, t1 = 0;
        for (int ee = 0; ee < E_NUM; ee++) {
            offsets[ee] = off;
            int n = s_count[ee];
            int nt2 = (n + 255) >> 8;
            for (int k = 0; k < nt2; k++) { tile_e256[t2] = ee; tile_r256[t2] = off + k * 256; t2++; }
            int nt1 = (n + 127) >> 7;
            for (int k = 0; k < nt1; k++) { tile_e128[t1] = ee; tile_r128[t1] = off + k * 128; t1++; }
            off += nt2 * 256;
        }
        offsets[E_NUM] = off;
        for (; t2 < T256_MAX; t2++) tile_e256[t2] = -1;
        for (; t1 < T128_MAX; t1++) tile_e128[t1] = -1;
        float s = 0.f;
        for (int ee = 0; ee < E_NUM; ee++) { float a = s_psum[ee] * (1.f / N_TOK); s += a * a; }
        aux_out[0] = 8.f * s;
    }
}

// ---------------- assign: block-aggregated slot reservation + inverse map ----------------
__global__ void assign_kernel(const int* __restrict__ topk_idx, const float* __restrict__ topk_w,
                              const int* __restrict__ offsets, int* __restrict__ count2,
                              int* __restrict__ slot_map, float* __restrict__ slot_w,
                              int* __restrict__ tok_slot) {
    __shared__ int h[E_NUM];
    __shared__ int base[E_NUM];
    if (threadIdx.x < E_NUM) h[threadIdx.x] = 0;
    __syncthreads();
    int item = blockIdx.x * 256 + threadIdx.x;
    int e = topk_idx[item];
    int rank = atomicAdd(&h[e], 1);         // LDS atomic
    __syncthreads();
    if (threadIdx.x < E_NUM)
        base[threadIdx.x] = offsets[threadIdx.x] + atomicAdd(&count2[threadIdx.x], h[threadIdx.x]);
    __syncthreads();
    int slot = base[e] + rank;
    slot_map[slot] = item;
    slot_w[slot] = topk_w[item];
    tok_slot[item] = slot;
}

// ---------------- gather: copy+convert x rows (fp32 -> bf16) into slot space ----------------
__global__ void gather_kernel(const float* __restrict__ x, const int* __restrict__ slot_map,
                              uint16_t* __restrict__ x_slots) {
    int slot = blockIdx.x;
    int item = slot_map[slot];
    if (item < 0) return;  // padding row: leave poison (garbage rows are row-contained in GEMMs)
    int t = item >> 1;
    float4 v = *(const float4*)(x + (size_t)t * C_DIM + threadIdx.x * 4);
    union { uint16_t u[4]; uint2 q; } r;
    r.u[0] = f2bf(v.x); r.u[1] = f2bf(v.y); r.u[2] = f2bf(v.z); r.u[3] = f2bf(v.w);
    *(uint2*)(x_slots + (size_t)slot * C_DIM + threadIdx.x * 4) = r.q;
}

// ---------------- convert+transpose fp32 [R][Cc] -> bf16 [Cc][R]; 64c x 128r tiles ----------------
// remap=1 (wv only): output row f -> n' interleaving gate/value at 16-col blocks:
//   b=f>>4; n' = (b<128 ? 2b : 2(b-128)+1)*16 + (f&15)
// so gemm1's 64-col wave slice holds gate frags at even nf, matching value frags at odd nf.
__global__ __launch_bounds__(256) void convT_kernel(const float* __restrict__ in,
                                                    uint16_t* __restrict__ out, int R, int Cc,
                                                    int remap) {
    __shared__ uint16_t s[128 * 66];
    size_t zb = (size_t)blockIdx.z * (size_t)R * Cc;
    int c0 = blockIdx.x * 64, r0 = blockIdx.y * 128;
    int cx = (threadIdx.x & 15) * 4, ry = threadIdx.x >> 4;
    for (int j = 0; j < 8; j++) {
        int r = ry + j * 16;
        float4 v = *(const float4*)(in + zb + (size_t)(r0 + r) * Cc + c0 + cx);
        uint16_t* p = &s[r * 66 + cx];
        p[0] = f2bf(v.x); p[1] = f2bf(v.y); p[2] = f2bf(v.z); p[3] = f2bf(v.w);
    }
    __syncthreads();
    int oc = threadIdx.x & 63, wseg = threadIdx.x >> 6;  // 4 waves, 32 rows each
    uint16_t tmp[32];
    for (int j = 0; j < 32; j++) tmp[j] = s[(wseg * 32 + j) * 66 + oc];
    int orow = c0 + oc;
    if (remap) {
        int b = orow >> 4;
        int nb = (b < 128) ? (b * 2) : ((b - 128) * 2 + 1);
        orow = nb * 16 + (orow & 15);
    }
    uint4* dst = (uint4*)(out + zb + (size_t)orow * R + r0 + wseg * 32);
    dst[0] = *(const uint4*)&tmp[0];
    dst[1] = *(const uint4*)&tmp[8];
    dst[2] = *(const uint4*)&tmp[16];
    dst[3] = *(const uint4*)&tmp[24];
}

// ================= GEMM1: 256x256 tile, BK=64, 8 waves, 8-phase counted-vmcnt schedule =================
// LDS: A/B each [2 dbuf][2 khalf] planes of [256 rows][32 k] bf16 (8192 elem/plane) = 128 KiB total.
// Staging swizzle sk + read swizzle cswz identical to the verified 128^2 kernel (bank-conflict 0).
// Schedule (iter i computes tiles 2i [buf0] and 2i+1 [buf1], BK=64 each, k-halves of 32):
//   ph1 (b0,k0,m0 +Bload): stage b1.Ak1(t2i+1)        ph5 (b1,k0,m0 +B): stage b0.Ak1(t2i+2)
//   ph2 (b0,k0,m1):        stage b1.Bk1(t2i+1) W      ph6 (b1,k0,m1):    stage b0.Bk1(t2i+2) W
//   ph3 (b0,k1,m0 +B):     stage b0.Ak0(t2i+2)        ph7 (b1,k1,m0 +B): stage b1.Ak0(t2i+3)
//   ph4 (b0,k1,m1):        stage b0.Bk0(t2i+2) W      ph8 (b1,k1,m1):    stage b1.Bk0(t2i+3) W
// W = s_waitcnt vmcnt(8) BEFORE the end-barrier (drain own 2 oldest halves; barrier then makes
// all waves' contributions visible before the next odd phase reads). 6 halves (12 loads) in flight.
// Every staged half is written only in phases strictly after its last reader's end-barrier.

#define A_OFF(b, h) (((b) * 2 + (h)) * 8192)
#define B_OFF(b, h) (32768 + ((b) * 2 + (h)) * 8192)

__global__ __launch_bounds__(512, 2) void gemm1_kernel(const uint16_t* __restrict__ x_slots,
                                                       const uint16_t* __restrict__ wvT,
                                                       const int* __restrict__ tile_e256,
                                                       const int* __restrict__ tile_r256,
                                                       uint16_t* __restrict__ act) {
    __shared__ uint16_t LDS[65536];  // 128 KiB
    int bid = blockIdx.x;                      // 0..639
    int swz = (bid & 7) * 80 + (bid >> 3);     // XCD chunk swizzle (640 = 8*80, bijective)
    int my = swz >> 4, j = swz & 15;           // j = n'-tile (fast dim for A reuse within chunk)
    int e = tile_e256[my];
    if (e < 0) return;
    int row0 = tile_r256[my];
    int lane = threadIdx.x & 63, v = threadIdx.x >> 6;
    int wm = v & 1, wn = v >> 1;               // 2M x 4N wave grid
    const uint16_t* wvb = wvT + (size_t)e * 4096 * 1024;

    int sk = ((lane & 3) ^ ((lane >> 3) & 3)) * 8;   // pre-swizzled global k-chunk for staging
    int srow = v * 32 + (lane >> 2);                 // staging row (q=0); q=1 adds 16
    const uint16_t* aSrc0 = x_slots + (size_t)(row0 + srow) * C_DIM + sk;
    const uint16_t* aSrc1 = aSrc0 + (size_t)16 * C_DIM;
    const uint16_t* bSrc0 = wvb + (size_t)(j * 256 + srow) * C_DIM + sk;
    const uint16_t* bSrc1 = bSrc0 + (size_t)16 * C_DIM;
    int cswz = ((lane >> 4) ^ ((lane >> 1) & 3)) * 8;  // swizzled LDS k-chunk for fragment reads

    f32x4 acc[8][4];
    f32x4 z4 = {0.f, 0.f, 0.f, 0.f};
#pragma unroll
    for (int m = 0; m < 8; m++)
#pragma unroll
        for (int n = 0; n < 4; n++) acc[m][n] = z4;
    s16x8 bfr[4];

#define STAGE_A(b, h, ko)                                              \
    do {                                                               \
        GLL16(aSrc0 + (ko) + (h) * 32, &LDS[A_OFF(b, h) + v * 1024]);  \
        GLL16(aSrc1 + (ko) + (h) * 32, &LDS[A_OFF(b, h) + v * 1024 + 512]); \
    } while (0)
#define STAGE_B(b, h, ko)                                              \
    do {                                                               \
        GLL16(bSrc0 + (ko) + (h) * 32, &LDS[B_OFF(b, h) + v * 1024]);  \
        GLL16(bSrc1 + (ko) + (h) * 32, &LDS[B_OFF(b, h) + v * 1024 + 512]); \
    } while (0)

#define PHASE(b, kh, mh, LB, STG, WEND)                                                        \
    do {                                                                                       \
        s16x8 af[4];                                                                           \
        _Pragma("unroll") for (int mf = 0; mf < 4; mf++)                                       \
            af[mf] = *(const s16x8*)&LDS[A_OFF(b, kh) +                                        \
                     (wm * 128 + ((mh) * 4 + mf) * 16 + (lane & 15)) * 32 + cswz];             \
        if (LB) {                                                                              \
            _Pragma("unroll") for (int nf = 0; nf < 4; nf++)                                   \
                bfr[nf] = *(const s16x8*)&LDS[B_OFF(b, kh) +                                   \
                          (wn * 64 + nf * 16 + (lane & 15)) * 32 + cswz];                      \
        }                                                                                      \
        STG;                                                                                   \
        asm volatile("s_barrier" ::: "memory");                                                \
        __builtin_amdgcn_s_setprio(1);                                                         \
        _Pragma("unroll") for (int mf = 0; mf < 4; mf++)                                       \
            _Pragma("unroll") for (int nf = 0; nf < 4; nf++)                                   \
                acc[(mh) * 4 + mf][nf] = __builtin_amdgcn_mfma_f32_16x16x32_bf16(              \
                    af[mf], bfr[nf], acc[(mh) * 4 + mf][nf], 0, 0, 0);                         \
        __builtin_amdgcn_s_setprio(0);                                                         \
        if (WEND) asm volatile("s_waitcnt vmcnt(8)" ::: "memory");                             \
        asm volatile("s_barrier" ::: "memory");                                                \
    } while (0)

    // reset vm/lgkm baseline so in-loop vmcnt counts only our GLL16s
    asm volatile("s_waitcnt vmcnt(0) lgkmcnt(0)" ::: "memory");
    // prologue: tile0 full into buf0, tile1 k0 into buf1 (oldest-first order matters)
    STAGE_A(0, 0, 0); STAGE_B(0, 0, 0);
    STAGE_A(0, 1, 0); STAGE_B(0, 1, 0);
    STAGE_A(1, 0, 64); STAGE_B(1, 0, 64);
    asm volatile("s_waitcnt vmcnt(8)" ::: "memory");  // drain buf0.k0 (A+B)
    asm volatile("s_barrier" ::: "memory");

    for (int i = 0; i < 8; i++) {  // 16 K-tiles of 64 => 8 iters x 2 tiles
        int ko1 = ((2 * i + 1) & 15) * 64;
        int ko2 = ((2 * i + 2) & 15) * 64;  // wraps harmlessly on tail
        int ko3 = ((2 * i + 3) & 15) * 64;
        PHASE(0, 0, 0, 1, STAGE_A(1, 1, ko1), 0);
        PHASE(0, 0, 1, 0, STAGE_B(1, 1, ko1), 1);
        PHASE(0, 1, 0, 1, STAGE_A(0, 0, ko2), 0);
        PHASE(0, 1, 1, 0, STAGE_B(0, 0, ko2), 1);
        PHASE(1, 0, 0, 1, STAGE_A(0, 1, ko2), 0);
        PHASE(1, 0, 1, 0, STAGE_B(0, 1, ko2), 1);
        PHASE(1, 1, 0, 1, STAGE_A(1, 0, ko3), 0);
        PHASE(1, 1, 1, 0, STAGE_B(1, 0, ko3), 1);
    }

    // epilogue: gate/value pairs are in-lane (nf even = gate, nf odd = value, same cols)
#pragma unroll
    for (int mfa = 0; mfa < 8; mfa++)
#pragma unroll
        for (int nfp = 0; nfp < 2; nfp++) {
            f32x4 g = acc[mfa][nfp * 2], vv = acc[mfa][nfp * 2 + 1];
#pragma unroll
            for (int r = 0; r < 4; r++) {
                int row = row0 + wm * 128 + mfa * 16 + (lane >> 4) * 4 + r;
                int f = j * 128 + wn * 32 + nfp * 16 + (lane & 15);
                float a = g[r] * vv[r] / (1.f + __expf(-g[r]));  // silu(g)*v
                act[(size_t)row * F_DIM + f] = f2bf(a);
            }
        }
#undef STAGE_A
#undef STAGE_B
#undef PHASE
}

// ---------------- GEMM2: eo[slot] = weight * (act @ c_proj[e]) ; 128x128 tile (round-0 structure) ----------------
__global__ __launch_bounds__(256) void gemm2_kernel(const uint16_t* __restrict__ act,
                                                    const uint16_t* __restrict__ cpT,
                                                    const int* __restrict__ tile_e128,
                                                    const int* __restrict__ tile_r128,
                                                    const int* __restrict__ slot_map,
                                                    const float* __restrict__ slot_w,
                                                    uint16_t* __restrict__ eo) {
    int e = tile_e128[blockIdx.y];
    if (e < 0) return;
    int row0 = tile_r128[blockIdx.y];
    int cb = blockIdx.x * 128;
    __shared__ uint16_t As[128 * 32];
    __shared__ uint16_t Bs[128 * 32];
    int lane = threadIdx.x & 63, w = threadIdx.x >> 6;
    int wm = w & 1, wn = w >> 1;
    const uint16_t* cpb = cpT + (size_t)e * 1024 * 2048;  // [n=1024][k=2048]

    int sk = (((lane & 3) ^ ((lane >> 3) & 3))) * 8;
    int ar = w * 32 + (lane >> 2);
    const uint16_t* agp0 = act + (size_t)(row0 + ar) * F_DIM + sk;
    const uint16_t* agp1 = agp0 + (size_t)16 * F_DIM;
    const uint16_t* bgp0 = cpb + (size_t)(cb + ar) * F_DIM + sk;
    const uint16_t* bgp1 = bgp0 + (size_t)16 * F_DIM;

    int cswz = ((lane >> 4) ^ ((lane >> 1) & 3)) * 8;

    f32x4 acc[4][4];
    f32x4 z4 = {0.f, 0.f, 0.f, 0.f};
    for (int mf = 0; mf < 4; mf++)
        for (int nf = 0; nf < 4; nf++) acc[mf][nf] = z4;

    for (int kt = 0; kt < 64; ++kt) {
        int ko = kt * 32;
        __syncthreads();
        GLL16(agp0 + ko, As + w * 1024);
        GLL16(agp1 + ko, As + w * 1024 + 512);
        GLL16(bgp0 + ko, Bs + w * 1024);
        GLL16(bgp1 + ko, Bs + w * 1024 + 512);
        __syncthreads();
        s16x8 af[4], bf[4];
        for (int mf = 0; mf < 4; mf++)
            af[mf] = *(const s16x8*)&As[(wm * 64 + mf * 16 + (lane & 15)) * 32 + cswz];
        for (int nf = 0; nf < 4; nf++)
            bf[nf] = *(const s16x8*)&Bs[(wn * 64 + nf * 16 + (lane & 15)) * 32 + cswz];
        for (int mf = 0; mf < 4; mf++)
            for (int nf = 0; nf < 4; nf++)
                acc[mf][nf] = __builtin_amdgcn_mfma_f32_16x16x32_bf16(af[mf], bf[nf], acc[mf][nf], 0, 0, 0);
    }
    for (int mf = 0; mf < 4; mf++)
        for (int r = 0; r < 4; r++) {
            int slotr = row0 + wm * 64 + mf * 16 + (lane >> 4) * 4 + r;
            int t2k = slot_map[slotr];
            if (t2k < 0) continue;  // padding row: skip (eo row never read)
            float wgt = slot_w[slotr];
            for (int nf = 0; nf < 4; nf++) {
                int col = cb + wn * 64 + nf * 16 + (lane & 15);
                eo[(size_t)slotr * C_DIM + col] = f2bf(wgt * acc[mf][nf][r]);
            }
        }
}

// ---------------- combine: out[t] = eo[slot0] + eo[slot1] (weights pre-applied) ----------------
__global__ void combine_kernel(const uint16_t* __restrict__ eo, const int* __restrict__ tok_slot,
                               float* __restrict__ out) {
    int t = blockIdx.x;
    int s0 = tok_slot[2 * t], s1 = tok_slot[2 * t + 1];
    int c = threadIdx.x * 4;
    uint2 a = *(const uint2*)(eo + (size_t)s0 * C_DIM + c);
    uint2 b = *(const uint2*)(eo + (size_t)s1 * C_DIM + c);
    float4 o;
    o.x = bf2f((uint16_t)(a.x & 0xffff)) + bf2f((uint16_t)(b.x & 0xffff));
    o.y = bf2f((uint16_t)(a.x >> 16)) + bf2f((uint16_t)(b.x >> 16));
    o.z = bf2f((uint16_t)(a.y & 0xffff)) + bf2f((uint16_t)(b.y & 0xffff));
    o.w = bf2f((uint16_t)(a.y >> 16)) + bf2f((uint16_t)(b.y >> 16));
    *(float4*)(out + (size_t)t * C_DIM + c) = o;
}

extern "C" void kernel_launch(void* const* d_in, const int* in_sizes, int n_in,
                              void* d_out, int out_size, void* d_ws, size_t ws_size,
                              hipStream_t stream) {
    (void)in_sizes; (void)n_in; (void)out_size; (void)ws_size;
    const float* x = (const float*)d_in[0];
    const float* rw = (const float*)d_in[1];
    const float* wv = (const float*)d_in[2];
    const float* cp = (const float*)d_in[3];
    float* out = (float*)d_out;

    char* ws = (char*)d_ws;
    size_t off = 0;
    auto alloc = [&](size_t sz) -> void* {
        off = (off + 255) & ~(size_t)255;
        void* p = ws + off;
        off += sz;
        return p;
    };
    uint16_t* wvT = (uint16_t*)alloc((size_t)E_NUM * 4096 * 1024 * 2);   // 64 MB
    uint16_t* cpT = (uint16_t*)alloc((size_t)E_NUM * 1024 * 2048 * 2);   // 32 MB
    uint16_t* x_slots = (uint16_t*)alloc((size_t)SMAX * C_DIM * 2);      // 20 MB
    uint16_t* act = (uint16_t*)alloc((size_t)SMAX * F_DIM * 2);          // 40 MB
    uint16_t* eo = x_slots;  // alias: x_slots dead after gemm1 reads it; gemm2 writes eo
    float* psum_part = (float*)alloc((size_t)RBLK * E_NUM * 4);
    int* cnt_part = (int*)alloc((size_t)RBLK * E_NUM * 4);
    int* count2 = (int*)alloc(E_NUM * 4);
    int* offsets = (int*)alloc((E_NUM + 1) * 4);
    int* tile_e256 = (int*)alloc(T256_MAX * 4);
    int* tile_r256 = (int*)alloc(T256_MAX * 4);
    int* tile_e128 = (int*)alloc(T128_MAX * 4);
    int* tile_r128 = (int*)alloc(T128_MAX * 4);
    int* topk_idx = (int*)alloc((size_t)N_TOK * 2 * 4);
    float* topk_w = (float*)alloc((size_t)N_TOK * 2 * 4);
    int* slot_map = (int*)alloc((size_t)SMAX * 4);
    float* slot_w = (float*)alloc((size_t)SMAX * 4);
    int* tok_slot = (int*)alloc((size_t)N_TOK * 2 * 4);

    hipMemsetAsync(count2, 0, E_NUM * 4, stream);
    hipMemsetAsync(slot_map, 0xFF, (size_t)SMAX * 4, stream);  // -1 => padding

    router_kernel<<<RBLK, 256, 0, stream>>>(x, rw, topk_idx, topk_w, psum_part, cnt_part);
    reduce_plan_kernel<<<1, 256, 0, stream>>>(psum_part, cnt_part, offsets, tile_e256, tile_r256,
                                              tile_e128, tile_r128, out + (size_t)N_TOK * C_DIM);
    assign_kernel<<<N_TOK * 2 / 256, 256, 0, stream>>>(topk_idx, topk_w, offsets, count2,
                                                       slot_map, slot_w, tok_slot);
    gather_kernel<<<SMAX, 256, 0, stream>>>(x, slot_map, x_slots);
    convT_kernel<<<dim3(4096 / 64, 1024 / 128, E_NUM), 256, 0, stream>>>(wv, wvT, 1024, 4096, 1);
    convT_kernel<<<dim3(1024 / 64, 2048 / 128, E_NUM), 256, 0, stream>>>(cp, cpT, 2048, 1024, 0);
    gemm1_kernel<<<16 * T256_MAX, 512, 0, stream>>>(x_slots, wvT, tile_e256, tile_r256, act);
    gemm2_kernel<<<dim3(8, T128_MAX), 256, 0, stream>>>(act, cpT, tile_e128, tile_r128,
                                                        slot_map, slot_w, eo);
    combine_kernel<<<N_TOK, 256, 0, stream>>>(eo, tok_slot, out);
}